// Round 15
// baseline (289.471 us; speedup 1.0000x reference)
//
#include <hip/hip_runtime.h>
#include <hip/hip_bf16.h>

#define NN 40000
#define EE 640000
#define ET 680000   // EE + NN self loops
#define MPAD 40064  // 313 * 128
#define LOG2E 1.4426950408889634f

// prep kernel index ranges
#define XN (MPAD * 128 / 4)          // conv_x items (4 elems each)
#define WN 131072                    // weight transpose items
#define VN 512                       // v projection items (layer-1 logit vectors)
#define UN 2048                      // u projection items (layer-0 logit vectors)
#define PREP_TOTAL (XN + WN + VN + UN + ET)

// fill_attn0 block ranges
#define FB ((ET + 255) / 256)        // csr_fill blocks
#define AB ((NN * 8 + 255) / 256)    // attn0 blocks

typedef __attribute__((ext_vector_type(8))) short short8;
typedef __attribute__((ext_vector_type(4))) float f32x4;

__device__ __forceinline__ float bf2f(unsigned u) {
    return __uint_as_float(u << 16);
}
__device__ __forceinline__ unsigned short f2bf(float f) {
    unsigned u = __float_as_uint(f);
    return (unsigned short)((u + 0x7FFFu + ((u >> 16) & 1u)) >> 16);
}
__device__ __forceinline__ unsigned pack2(float lo, float hi) {
    return ((unsigned)f2bf(lo)) | (((unsigned)f2bf(hi)) << 16);
}
__device__ __forceinline__ void unpack2(unsigned u, float& lo, float& hi) {
    lo = __uint_as_float(u << 16);
    hi = __uint_as_float(u & 0xffff0000u);
}

// -- prep: conv_x | weight transposes | v proj | u proj | csr_count(+edge rank) --
__global__ __launch_bounds__(256) void prep(
    const float* __restrict__ x, const float* __restrict__ W0,
    const float* __restrict__ Ws, const float* __restrict__ W1,
    const float* __restrict__ as0, const float* __restrict__ ad0,
    const float* __restrict__ as1, const float* __restrict__ ad1,
    const int* __restrict__ ei,
    unsigned short* __restrict__ xb, unsigned short* __restrict__ Wtc,
    unsigned short* __restrict__ W1t, float* __restrict__ v, float* __restrict__ u,
    int* __restrict__ deg, int* __restrict__ erank)
{
    int i = blockIdx.x * 256 + threadIdx.x;
    if (i < XN) {
        int row = (i * 4) >> 7;
        ushort4 o;
        if (row < NN) {
            float4 val = ((const float4*)x)[i];
            o.x = f2bf(val.x); o.y = f2bf(val.y); o.z = f2bf(val.z); o.w = f2bf(val.w);
        } else { o.x = o.y = o.z = o.w = 0; }
        ((ushort4*)xb)[i] = o;
    } else if (i < XN + WN) {
        int j = i - XN;
        if (j < 32768) {
            int c = j >> 7, k = j & 127;
            Wtc[j] = f2bf(W0[(size_t)k * 256 + c]);
        } else if (j < 65536) {
            int jj = j - 32768;
            int c = jj >> 7, k = jj & 127;
            Wtc[j] = f2bf(Ws[(size_t)k * 256 + c]);
        } else {
            int jj = j - 65536;
            int c = jj >> 8, k = jj & 255;
            W1t[jj] = f2bf(W1[(size_t)k * 256 + c]);
        }
    } else if (i < XN + WN + VN) {
        int j = i - XN - WN;         // [0,512)
        int k = j >> 1, which = j & 1;
        const float* att = which ? ad1 : as1;
        float sum = 0.f;
        for (int c = 0; c < 256; c++)
            sum += W1[(size_t)k * 256 + c] * att[c];
        v[j] = sum * LOG2E;
    } else if (i < XN + WN + VN + UN) {
        int j = i - XN - WN - VN;    // [0,2048): k = j>>4, jj = j&15
        int k = j >> 4, jj = j & 15;
        int h = jj & 7;
        const float* att = (jj < 8) ? as0 : ad0;
        float sum = 0.f;
        #pragma unroll
        for (int c = 0; c < 32; c++)
            sum += W0[(size_t)k * 256 + h * 32 + c] * att[h * 32 + c];
        u[j] = sum * LOG2E;
    } else {
        int e = i - XN - WN - VN - UN;
        if (e < ET) {
            int d = (e < EE) ? ei[EE + e] : (e - EE);
            erank[e] = atomicAdd(&deg[d], 1);   // rank within dst row
        }
    }
}

// ---------------- exscan (single block, shfl-based) ----------------
__global__ __launch_bounds__(1024) void exscan(
    const int* __restrict__ deg, int* __restrict__ rowptr)
{
    __shared__ int wsum[16];
    __shared__ int carry_s;
    int tid = threadIdx.x, lane = tid & 63, wid = tid >> 6;
    if (tid == 0) carry_s = 0;
    __syncthreads();
    for (int base = 0; base < NN; base += 1024) {
        int i = base + tid;
        int val = (i < NN) ? deg[i] : 0;
        int sc = val;
        #pragma unroll
        for (int off = 1; off < 64; off <<= 1) {
            int t = __shfl_up(sc, off);
            if (lane >= off) sc += t;
        }
        if (lane == 63) wsum[wid] = sc;
        __syncthreads();
        if (wid == 0 && lane < 16) {
            int t = wsum[lane];
            #pragma unroll
            for (int off = 1; off < 16; off <<= 1) {
                int uu = __shfl_up(t, off);
                if (lane >= off) t += uu;
            }
            wsum[lane] = t;
        }
        __syncthreads();
        int carry = carry_s;
        int wpre = wid ? wsum[wid - 1] : 0;
        int excl = carry + wpre + sc - val;
        if (i < NN) rowptr[i] = excl;
        __syncthreads();
        if (tid == 0) carry_s = carry + wsum[15];
    }
    if (tid == 0) rowptr[NN] = carry_s;
}

// -------- merged: csr_fill (atomic-free) | attn0 (layer-0 logits from x @ u) --------
__global__ __launch_bounds__(256) void fill_attn0(
    const int* __restrict__ ei, const int* __restrict__ rowptr,
    const int* __restrict__ erank, int* __restrict__ adj,
    const unsigned short* __restrict__ xb, const float* __restrict__ u,
    float* __restrict__ a_s, float* __restrict__ a_d)
{
    int tid = threadIdx.x;
    if (blockIdx.x < FB) {
        int e = blockIdx.x * 256 + tid;
        if (e >= ET) return;
        int s, d;
        if (e < EE) { s = ei[e]; d = ei[EE + e]; } else { s = d = e - EE; }
        adj[rowptr[d] + erank[e]] = s;
        return;
    }
    int t = (blockIdx.x - FB) * 256 + tid;
    if (t >= NN * 8) return;
    int n = t >> 3, h = t & 7;
    const uint4* xr = (const uint4*)(xb + (size_t)n * 128);
    float s = 0.f, dd = 0.f;
    #pragma unroll
    for (int q = 0; q < 16; q++) {        // 16 x uint4 = 128 channels
        uint4 raw = xr[q];
        unsigned vals[4] = {raw.x, raw.y, raw.z, raw.w};
        #pragma unroll
        for (int r = 0; r < 4; r++) {
            float lo, hi;
            unpack2(vals[r], lo, hi);
            int c = q * 8 + r * 2;
            s  += lo * u[c * 16 + h]     + hi * u[(c + 1) * 16 + h];
            dd += lo * u[c * 16 + 8 + h] + hi * u[(c + 1) * 16 + 8 + h];
        }
    }
    a_s[t] = s; a_d[t] = dd;
}

// ---------------- GEMM0: dual-output (xp | skip): A[MPAD][128] @ Wtc[512][128]^T ----
__global__ __launch_bounds__(256) void gemm0(
    const unsigned short* __restrict__ A, const unsigned short* __restrict__ Btc,
    unsigned short* __restrict__ C0, unsigned short* __restrict__ C1)
{
    __shared__ unsigned short As[128 * 64];
    const int K = 128;
    int tid = threadIdx.x;
    int rb = blockIdx.x * 128, cb = blockIdx.y * 128;
    int lane = tid & 63, wid = tid >> 6;
    int wm = (wid >> 1) * 64, wn = (wid & 1) * 64;
    int lr = lane & 15, lk = lane >> 4;
    f32x4 acc[4][4] = {};
    for (int kb = 0; kb < K; kb += 64) {
        #pragma unroll
        for (int i = 0; i < 4; i++) {
            int flat = tid + i * 256;
            int r = flat >> 3, c8 = flat & 7;
            int4 vv = *(const int4*)(A + (size_t)(rb + r) * K + kb + c8 * 8);
            *(int4*)(&As[r * 64 + ((c8 ^ (r & 7)) * 8)]) = vv;
        }
        __syncthreads();
        #pragma unroll
        for (int kk = 0; kk < 2; kk++) {
            int kbase = kb + kk * 32 + lk * 8;
            short8 bfr[4], afr[4];
            #pragma unroll
            for (int n = 0; n < 4; n++)
                bfr[n] = *(const short8*)(Btc + (size_t)(cb + wn + n * 16 + lr) * K + kbase);
            #pragma unroll
            for (int m = 0; m < 4; m++) {
                int row = wm + m * 16 + lr;
                int kchunk = kk * 4 + lk;
                afr[m] = *(const short8*)(&As[row * 64 + ((kchunk ^ (row & 7)) * 8)]);
            }
            #pragma unroll
            for (int m = 0; m < 4; m++)
                #pragma unroll
                for (int n = 0; n < 4; n++)
                    acc[m][n] = __builtin_amdgcn_mfma_f32_16x16x32_bf16(afr[m], bfr[n], acc[m][n], 0, 0, 0);
        }
        __syncthreads();
    }
    unsigned short* C = (cb < 256) ? C0 : C1;
    int cbase = cb & 255;
    #pragma unroll
    for (int m = 0; m < 4; m++)
        #pragma unroll
        for (int n = 0; n < 4; n++) {
            int col = cbase + wn + n * 16 + lr;
            #pragma unroll
            for (int j = 0; j < 4; j++) {
                int row = rb + wm + m * 16 + lk * 4 + j;
                C[(size_t)row * 256 + col] = f2bf(acc[m][n][j]);
            }
        }
}

// ---------------- GEMM1: xp1[MPAD][256] = h @ W1t^T (grid y=2) ----------------
__global__ __launch_bounds__(256) void gemm_bf16(
    const unsigned short* __restrict__ A, const unsigned short* __restrict__ Btc,
    unsigned short* __restrict__ C0, int K)
{
    __shared__ unsigned short As[128 * 64];
    int tid = threadIdx.x;
    int rb = blockIdx.x * 128, cb = blockIdx.y * 128;
    int lane = tid & 63, wid = tid >> 6;
    int wm = (wid >> 1) * 64, wn = (wid & 1) * 64;
    int lr = lane & 15, lk = lane >> 4;
    f32x4 acc[4][4] = {};
    for (int kb = 0; kb < K; kb += 64) {
        #pragma unroll
        for (int i = 0; i < 4; i++) {
            int flat = tid + i * 256;
            int r = flat >> 3, c8 = flat & 7;
            int4 vv = *(const int4*)(A + (size_t)(rb + r) * K + kb + c8 * 8);
            *(int4*)(&As[r * 64 + ((c8 ^ (r & 7)) * 8)]) = vv;
        }
        __syncthreads();
        #pragma unroll
        for (int kk = 0; kk < 2; kk++) {
            int kbase = kb + kk * 32 + lk * 8;
            short8 bfr[4], afr[4];
            #pragma unroll
            for (int n = 0; n < 4; n++)
                bfr[n] = *(const short8*)(Btc + (size_t)(cb + wn + n * 16 + lr) * K + kbase);
            #pragma unroll
            for (int m = 0; m < 4; m++) {
                int row = wm + m * 16 + lr;
                int kchunk = kk * 4 + lk;
                afr[m] = *(const short8*)(&As[row * 64 + ((kchunk ^ (row & 7)) * 8)]);
            }
            #pragma unroll
            for (int m = 0; m < 4; m++)
                #pragma unroll
                for (int n = 0; n < 4; n++)
                    acc[m][n] = __builtin_amdgcn_mfma_f32_16x16x32_bf16(afr[m], bfr[n], acc[m][n], 0, 0, 0);
        }
        __syncthreads();
    }
    #pragma unroll
    for (int m = 0; m < 4; m++)
        #pragma unroll
        for (int n = 0; n < 4; n++) {
            int col = cb + wn + n * 16 + lr;
            #pragma unroll
            for (int j = 0; j < 4; j++) {
                int row = rb + wm + m * 16 + lk * 4 + j;
                C0[(size_t)row * 256 + col] = f2bf(acc[m][n][j]);
            }
        }
}

// ---------------- gather0: half-wave edges, 8 ch/lane (R8-proven) ------------
__global__ __launch_bounds__(256) void gather0(
    const int* __restrict__ adj, const int* __restrict__ rowptr,
    const unsigned short* __restrict__ xp, const float* __restrict__ a_s,
    const float* __restrict__ a_d, unsigned short* __restrict__ out0)
{
    int w = (blockIdx.x * 256 + threadIdx.x) >> 6;
    int lane = threadIdx.x & 63;
    if (w >= NN) return;
    int hl = lane & 31;               // half-lane
    int hw = lane >> 5;               // which half-wave
    int h = hl >> 2;                  // head = (8*hl)/32
    float ad = a_d[w * 8 + h];
    int p = rowptr[w], end = rowptr[w + 1];
    unsigned loff = (unsigned)hl * 16u;
    float a0=0,a1=0,a2=0,a3=0,a4=0,a5=0,a6=0,a7=0;
    float b0=0,b1=0,b2=0,b3=0,b4=0,b5=0,b6=0,b7=0;
    float den0 = 0.f, den1 = 0.f;
    float lo, hi;
    for (; p + 4 <= end; p += 4) {
        int sA = adj[p + hw];
        int sB = adj[p + 2 + hw];
        float eA = a_s[sA * 8 + h] + ad;
        float eB = a_s[sB * 8 + h] + ad;
        float wA = __builtin_amdgcn_exp2f(fmaxf(eA, 0.2f * eA));
        float wB = __builtin_amdgcn_exp2f(fmaxf(eB, 0.2f * eB));
        uint4 rA = *(const uint4*)((const char*)xp + ((unsigned)sA * 512u + loff));
        uint4 rB = *(const uint4*)((const char*)xp + ((unsigned)sB * 512u + loff));
        den0 += wA; den1 += wB;
        unpack2(rA.x, lo, hi); a0 += wA * lo; a1 += wA * hi;
        unpack2(rA.y, lo, hi); a2 += wA * lo; a3 += wA * hi;
        unpack2(rA.z, lo, hi); a4 += wA * lo; a5 += wA * hi;
        unpack2(rA.w, lo, hi); a6 += wA * lo; a7 += wA * hi;
        unpack2(rB.x, lo, hi); b0 += wB * lo; b1 += wB * hi;
        unpack2(rB.y, lo, hi); b2 += wB * lo; b3 += wB * hi;
        unpack2(rB.z, lo, hi); b4 += wB * lo; b5 += wB * hi;
        unpack2(rB.w, lo, hi); b6 += wB * lo; b7 += wB * hi;
    }
    for (; p + 2 <= end; p += 2) {
        int sA = adj[p + hw];
        float eA = a_s[sA * 8 + h] + ad;
        float wA = __builtin_amdgcn_exp2f(fmaxf(eA, 0.2f * eA));
        uint4 rA = *(const uint4*)((const char*)xp + ((unsigned)sA * 512u + loff));
        den0 += wA;
        unpack2(rA.x, lo, hi); a0 += wA * lo; a1 += wA * hi;
        unpack2(rA.y, lo, hi); a2 += wA * lo; a3 += wA * hi;
        unpack2(rA.z, lo, hi); a4 += wA * lo; a5 += wA * hi;
        unpack2(rA.w, lo, hi); a6 += wA * lo; a7 += wA * hi;
    }
    if (p < end) {                     // single tail edge: half A only
        int sA = adj[p];
        float eA = a_s[sA * 8 + h] + ad;
        float wA = hw ? 0.f : __builtin_amdgcn_exp2f(fmaxf(eA, 0.2f * eA));
        uint4 rA = *(const uint4*)((const char*)xp + ((unsigned)sA * 512u + loff));
        den0 += wA;
        unpack2(rA.x, lo, hi); a0 += wA * lo; a1 += wA * hi;
        unpack2(rA.y, lo, hi); a2 += wA * lo; a3 += wA * hi;
        unpack2(rA.z, lo, hi); a4 += wA * lo; a5 += wA * hi;
        unpack2(rA.w, lo, hi); a6 += wA * lo; a7 += wA * hi;
    }
    a0 += b0; a1 += b1; a2 += b2; a3 += b3;
    a4 += b4; a5 += b5; a6 += b6; a7 += b7;
    float den = den0 + den1;
    den += __shfl_xor(den, 32);
    a0 += __shfl_xor(a0, 32); a1 += __shfl_xor(a1, 32);
    a2 += __shfl_xor(a2, 32); a3 += __shfl_xor(a3, 32);
    a4 += __shfl_xor(a4, 32); a5 += __shfl_xor(a5, 32);
    a6 += __shfl_xor(a6, 32); a7 += __shfl_xor(a7, 32);
    if (hw == 0) {
        float inv = 1.f / (den + 1e-16f);
        uint4 o;
        o.x = pack2(a0 * inv, a1 * inv);
        o.y = pack2(a2 * inv, a3 * inv);
        o.z = pack2(a4 * inv, a5 * inv);
        o.w = pack2(a6 * inv, a7 * inv);
        *(uint4*)((char*)out0 + ((size_t)w * 512u + loff)) = o;
    }
}

// ---------------- BN column stats (bf16 input) ----------------
__global__ __launch_bounds__(256) void bn_stats(
    const unsigned short* __restrict__ H, float* __restrict__ bnsum, float* __restrict__ bnsq)
{
    int c = threadIdx.x;
    int r0 = blockIdx.x * 64;
    float s = 0.f, sq = 0.f;
    for (int r = r0; r < r0 + 64; r++) {
        float val = bf2f(H[(size_t)r * 256 + c]);
        s += val; sq += val * val;
    }
    atomicAdd(&bnsum[c], s);
    atomicAdd(&bnsq[c], sq);
}

// ---------------- h = elu(bn(out0)) + skip ; fused layer-1 logits a1 = h @ v --------
__global__ __launch_bounds__(256) void bn_elu_attn(
    const unsigned short* __restrict__ out0, unsigned short* __restrict__ hb,
    const float* __restrict__ bnsum, const float* __restrict__ bnsq,
    const float* __restrict__ gamma, const float* __restrict__ beta,
    const float* __restrict__ bskip, const float* __restrict__ v,
    float* __restrict__ a_s, float* __restrict__ a_d)
{
    int i = blockIdx.x * 256 + threadIdx.x;   // one per 8 elems; 32 threads per row
    if (i >= MPAD * 32) return;
    int col0 = (i * 8) & 255;
    int row = i >> 5;
    uint4 hv = ((const uint4*)out0)[i];
    uint4 sv = ((const uint4*)hb)[i];
    float bn[8], sk[8];
    unpack2(hv.x, bn[0], bn[1]); unpack2(hv.y, bn[2], bn[3]);
    unpack2(hv.z, bn[4], bn[5]); unpack2(hv.w, bn[6], bn[7]);
    unpack2(sv.x, sk[0], sk[1]); unpack2(sv.y, sk[2], sk[3]);
    unpack2(sv.z, sk[4], sk[5]); unpack2(sv.w, sk[6], sk[7]);
    const float invN = 1.0f / (float)NN;
    float r[8];
    float ps = 0.f, pd = 0.f;
    #pragma unroll
    for (int q = 0; q < 8; q++) {
        int c = col0 + q;
        float mu = bnsum[c] * invN;
        float var = bnsq[c] * invN - mu * mu;
        float scl = rsqrtf(var + 1e-5f) * gamma[c];
        float b = (bn[q] - mu) * scl + beta[c];
        float el = b > 0.f ? b : (__expf(b) - 1.f);
        r[q] = el + sk[q] + bskip[c];
        float2 vv = *(const float2*)(v + c * 2);
        ps += r[q] * vv.x;
        pd += r[q] * vv.y;
    }
    uint4 o;
    o.x = pack2(r[0], r[1]); o.y = pack2(r[2], r[3]);
    o.z = pack2(r[4], r[5]); o.w = pack2(r[6], r[7]);
    ((uint4*)hb)[i] = o;
    #pragma unroll
    for (int off = 1; off < 32; off <<= 1) {
        ps += __shfl_xor(ps, off);
        pd += __shfl_xor(pd, off);
    }
    if ((threadIdx.x & 31) == 0 && row < NN) {
        a_s[row] = ps;
        a_d[row] = pd;
    }
}

// ---------------- gather1: half-wave edges (1 head), +b1, f32 out (R8-proven) -------
__global__ __launch_bounds__(256) void gather1(
    const int* __restrict__ adj, const int* __restrict__ rowptr,
    const unsigned short* __restrict__ xp, const float* __restrict__ a_s,
    const float* __restrict__ a_d, const float* __restrict__ b1,
    float* __restrict__ out)
{
    int w = (blockIdx.x * 256 + threadIdx.x) >> 6;
    int lane = threadIdx.x & 63;
    if (w >= NN) return;
    int hl = lane & 31;
    int hw = lane >> 5;
    float ad = a_d[w];
    int p = rowptr[w], end = rowptr[w + 1];
    unsigned loff = (unsigned)hl * 16u;
    float a0=0,a1=0,a2=0,a3=0,a4=0,a5=0,a6=0,a7=0;
    float b0s=0,b1s=0,b2s=0,b3s=0,b4s=0,b5s=0,b6s=0,b7s=0;
    float den0 = 0.f, den1 = 0.f;
    float lo, hi;
    for (; p + 4 <= end; p += 4) {
        int sA = adj[p + hw];
        int sB = adj[p + 2 + hw];
        float eA = a_s[sA] + ad;
        float eB = a_s[sB] + ad;
        float wA = __builtin_amdgcn_exp2f(fmaxf(eA, 0.2f * eA));
        float wB = __builtin_amdgcn_exp2f(fmaxf(eB, 0.2f * eB));
        uint4 rA = *(const uint4*)((const char*)xp + ((unsigned)sA * 512u + loff));
        uint4 rB = *(const uint4*)((const char*)xp + ((unsigned)sB * 512u + loff));
        den0 += wA; den1 += wB;
        unpack2(rA.x, lo, hi); a0 += wA * lo; a1 += wA * hi;
        unpack2(rA.y, lo, hi); a2 += wA * lo; a3 += wA * hi;
        unpack2(rA.z, lo, hi); a4 += wA * lo; a5 += wA * hi;
        unpack2(rA.w, lo, hi); a6 += wA * lo; a7 += wA * hi;
        unpack2(rB.x, lo, hi); b0s += wB * lo; b1s += wB * hi;
        unpack2(rB.y, lo, hi); b2s += wB * lo; b3s += wB * hi;
        unpack2(rB.z, lo, hi); b4s += wB * lo; b5s += wB * hi;
        unpack2(rB.w, lo, hi); b6s += wB * lo; b7s += wB * hi;
    }
    for (; p + 2 <= end; p += 2) {
        int sA = adj[p + hw];
        float eA = a_s[sA] + ad;
        float wA = __builtin_amdgcn_exp2f(fmaxf(eA, 0.2f * eA));
        uint4 rA = *(const uint4*)((const char*)xp + ((unsigned)sA * 512u + loff));
        den0 += wA;
        unpack2(rA.x, lo, hi); a0 += wA * lo; a1 += wA * hi;
        unpack2(rA.y, lo, hi); a2 += wA * lo; a3 += wA * hi;
        unpack2(rA.z, lo, hi); a4 += wA * lo; a5 += wA * hi;
        unpack2(rA.w, lo, hi); a6 += wA * lo; a7 += wA * hi;
    }
    if (p < end) {
        int sA = adj[p];
        float eA = a_s[sA] + ad;
        float wA = hw ? 0.f : __builtin_amdgcn_exp2f(fmaxf(eA, 0.2f * eA));
        uint4 rA = *(const uint4*)((const char*)xp + ((unsigned)sA * 512u + loff));
        den0 += wA;
        unpack2(rA.x, lo, hi); a0 += wA * lo; a1 += wA * hi;
        unpack2(rA.y, lo, hi); a2 += wA * lo; a3 += wA * hi;
        unpack2(rA.z, lo, hi); a4 += wA * lo; a5 += wA * hi;
        unpack2(rA.w, lo, hi); a6 += wA * lo; a7 += wA * hi;
    }
    a0 += b0s; a1 += b1s; a2 += b2s; a3 += b3s;
    a4 += b4s; a5 += b5s; a6 += b6s; a7 += b7s;
    float den = den0 + den1;
    den += __shfl_xor(den, 32);
    a0 += __shfl_xor(a0, 32); a1 += __shfl_xor(a1, 32);
    a2 += __shfl_xor(a2, 32); a3 += __shfl_xor(a3, 32);
    a4 += __shfl_xor(a4, 32); a5 += __shfl_xor(a5, 32);
    a6 += __shfl_xor(a6, 32); a7 += __shfl_xor(a7, 32);
    if (hw == 0) {
        float inv = 1.f / (den + 1e-16f);
        const float* bb = b1 + hl * 8;
        float4 o0 = {a0 * inv + bb[0], a1 * inv + bb[1],
                     a2 * inv + bb[2], a3 * inv + bb[3]};
        float4 o1 = {a4 * inv + bb[4], a5 * inv + bb[5],
                     a6 * inv + bb[6], a7 * inv + bb[7]};
        float* orow = out + (size_t)w * 256 + hl * 8;
        *(float4*)(orow) = o0;
        *(float4*)(orow + 4) = o1;
    }
}

extern "C" void kernel_launch(void* const* d_in, const int* in_sizes, int n_in,
                              void* d_out, int out_size, void* d_ws, size_t ws_size,
                              hipStream_t stream)
{
    const float* x      = (const float*)d_in[0];
    const int*   ei     = (const int*)d_in[1];
    const float* W0     = (const float*)d_in[2];
    const float* att_s0 = (const float*)d_in[3];
    const float* att_d0 = (const float*)d_in[4];
    // b0 (d_in[5]) cancels under BatchNorm -> unused
    const float* gamma0 = (const float*)d_in[6];
    const float* beta0  = (const float*)d_in[7];
    const float* W_skip = (const float*)d_in[8];
    const float* b_skip = (const float*)d_in[9];
    const float* W1     = (const float*)d_in[10];
    const float* att_s1 = (const float*)d_in[11];
    const float* att_d1 = (const float*)d_in[12];
    const float* b1     = (const float*)d_in[13];
    float* out = (float*)d_out;

    // workspace layout (deg..bnsq contiguous for single memset)
    char* p = (char*)d_ws;
    unsigned short* x_bf  = (unsigned short*)p; p += (size_t)MPAD * 128 * 2;
    unsigned short* xp_bf = (unsigned short*)p; p += (size_t)MPAD * 256 * 2;  // xp0 then xp1
    unsigned short* h_bf  = (unsigned short*)p; p += (size_t)MPAD * 256 * 2;  // skip, then h in place
    unsigned short* out0b = (unsigned short*)p; p += (size_t)MPAD * 256 * 2;
    unsigned short* Wtc   = (unsigned short*)p; p += (size_t)512 * 128 * 2;   // [W0t | Wst]
    unsigned short* W1t   = (unsigned short*)p; p += (size_t)256 * 256 * 2;
    float* v     = (float*)p; p += 512 * 4;
    float* u     = (float*)p; p += 2048 * 4;
    float* a_s   = (float*)p; p += (size_t)NN * 8 * 4;
    float* a_d   = (float*)p; p += (size_t)NN * 8 * 4;
    int*   deg   = (int*)p;   p += (size_t)NN * 4;
    float* bnsum = (float*)p; p += 256 * 4;
    float* bnsq  = (float*)p; p += 256 * 4;
    int* rowptr = (int*)p; p += (size_t)(NN + 1) * 4;
    int* erank  = (int*)p; p += (size_t)ET * 4;
    int* adj    = (int*)p; p += (size_t)ET * 4;

    // one memset covers deg + bnsum + bnsq (contiguous)
    hipMemsetAsync(deg, 0, (size_t)(NN + 512) * 4, stream);
    // deterministic pad rows for out0b (never written by gather0)
    hipMemsetAsync(out0b + (size_t)NN * 256, 0, (size_t)(MPAD - NN) * 256 * 2, stream);

    // phase 1: converts + u/v projections + csr_count(+rank) (one kernel)
    prep<<<(PREP_TOTAL + 255) / 256, 256, 0, stream>>>(
        x, W0, W_skip, W1, att_s0, att_d0, att_s1, att_d1, ei,
        x_bf, Wtc, W1t, v, u, deg, erank);

    // phase 2: exscan
    exscan<<<1, 1024, 0, stream>>>(deg, rowptr);

    // phase 3: csr_fill | layer-0 logits (merged, both low-resource)
    fill_attn0<<<FB + AB, 256, 0, stream>>>(ei, rowptr, erank, adj, x_bf, u, a_s, a_d);

    // phase 4: GEMM0 (dual output xp | skip)
    dim3 gg0(MPAD / 128, 4);
    gemm0<<<gg0, 256, 0, stream>>>(x_bf, Wtc, xp_bf, h_bf);

    // phase 5: gather0
    gather0<<<(NN * 64 + 255) / 256, 256, 0, stream>>>(adj, rowptr, xp_bf, a_s, a_d, out0b);

    // phase 6: BN stats
    bn_stats<<<NN / 64, 256, 0, stream>>>(out0b, bnsum, bnsq);

    // phase 7: BN + ELU + skip, fused layer-1 logits
    bn_elu_attn<<<(MPAD * 32 + 255) / 256, 256, 0, stream>>>(
        out0b, h_bf, bnsum, bnsq, gamma0, beta0, b_skip, v, a_s, a_d);

    // phase 8: GEMM1
    dim3 gg1(MPAD / 128, 2);
    gemm_bf16<<<gg1, 256, 0, stream>>>(h_bf, W1t, xp_bf, 256);

    // phase 9: gather1
    gather1<<<(NN * 64 + 255) / 256, 256, 0, stream>>>(adj, rowptr, xp_bf, a_s, a_d, b1, out);
}

// Round 17
// 288.214 us; speedup vs baseline: 1.0044x; 1.0044x over previous
//
#include <hip/hip_runtime.h>
#include <hip/hip_bf16.h>

#define NN 40000
#define EE 640000
#define ET 680000   // EE + NN self loops
#define MPAD 40064  // 313 * 128
#define LOG2E 1.4426950408889634f

// prep kernel index ranges
#define XN (MPAD * 128 / 4)          // conv_x items (4 elems each)
#define WN 131072                    // weight transpose items
#define VN 512                       // v projection items (layer-1 logit vectors)
#define UN 2048                      // u projection items (layer-0 logit vectors)
#define PREP_TOTAL (XN + WN + VN + UN + ET)

// fill_attn0 block ranges
#define FB ((ET + 255) / 256)        // csr_fill blocks
#define AB ((NN * 8 + 255) / 256)    // attn0 blocks

typedef __attribute__((ext_vector_type(8))) short short8;
typedef __attribute__((ext_vector_type(4))) float f32x4;

__device__ __forceinline__ float bf2f(unsigned u) {
    return __uint_as_float(u << 16);
}
__device__ __forceinline__ unsigned short f2bf(float f) {
    unsigned u = __float_as_uint(f);
    return (unsigned short)((u + 0x7FFFu + ((u >> 16) & 1u)) >> 16);
}
__device__ __forceinline__ unsigned pack2(float lo, float hi) {
    return ((unsigned)f2bf(lo)) | (((unsigned)f2bf(hi)) << 16);
}
__device__ __forceinline__ void unpack2(unsigned u, float& lo, float& hi) {
    lo = __uint_as_float(u << 16);
    hi = __uint_as_float(u & 0xffff0000u);
}

// -- prep: conv_x | weight transposes | v proj | u proj | csr_count(+edge rank) --
__global__ __launch_bounds__(256) void prep(
    const float* __restrict__ x, const float* __restrict__ W0,
    const float* __restrict__ Ws, const float* __restrict__ W1,
    const float* __restrict__ as0, const float* __restrict__ ad0,
    const float* __restrict__ as1, const float* __restrict__ ad1,
    const int* __restrict__ ei,
    unsigned short* __restrict__ xb, unsigned short* __restrict__ Wtc,
    unsigned short* __restrict__ W1t, float* __restrict__ v, float* __restrict__ u,
    int* __restrict__ deg, int* __restrict__ erank)
{
    int i = blockIdx.x * 256 + threadIdx.x;
    if (i < XN) {
        int row = (i * 4) >> 7;
        ushort4 o;
        if (row < NN) {
            float4 val = ((const float4*)x)[i];
            o.x = f2bf(val.x); o.y = f2bf(val.y); o.z = f2bf(val.z); o.w = f2bf(val.w);
        } else { o.x = o.y = o.z = o.w = 0; }
        ((ushort4*)xb)[i] = o;
    } else if (i < XN + WN) {
        int j = i - XN;
        if (j < 32768) {
            int c = j >> 7, k = j & 127;
            Wtc[j] = f2bf(W0[(size_t)k * 256 + c]);
        } else if (j < 65536) {
            int jj = j - 32768;
            int c = jj >> 7, k = jj & 127;
            Wtc[j] = f2bf(Ws[(size_t)k * 256 + c]);
        } else {
            int jj = j - 65536;
            int c = jj >> 8, k = jj & 255;
            W1t[jj] = f2bf(W1[(size_t)k * 256 + c]);
        }
    } else if (i < XN + WN + VN) {
        int j = i - XN - WN;         // [0,512)
        int k = j >> 1, which = j & 1;
        const float* att = which ? ad1 : as1;
        float sum = 0.f;
        for (int c = 0; c < 256; c++)
            sum += W1[(size_t)k * 256 + c] * att[c];
        v[j] = sum * LOG2E;
    } else if (i < XN + WN + VN + UN) {
        int j = i - XN - WN - VN;    // [0,2048): k = j>>4, jj = j&15
        int k = j >> 4, jj = j & 15;
        int h = jj & 7;
        const float* att = (jj < 8) ? as0 : ad0;
        float sum = 0.f;
        #pragma unroll
        for (int c = 0; c < 32; c++)
            sum += W0[(size_t)k * 256 + h * 32 + c] * att[h * 32 + c];
        u[j] = sum * LOG2E;
    } else {
        int e = i - XN - WN - VN - UN;
        if (e < ET) {
            int d = (e < EE) ? ei[EE + e] : (e - EE);
            erank[e] = atomicAdd(&deg[d], 1);   // rank within dst row
        }
    }
}

// ---------------- exscan (single block, shfl-based) ----------------
__global__ __launch_bounds__(1024) void exscan(
    const int* __restrict__ deg, int* __restrict__ rowptr)
{
    __shared__ int wsum[16];
    __shared__ int carry_s;
    int tid = threadIdx.x, lane = tid & 63, wid = tid >> 6;
    if (tid == 0) carry_s = 0;
    __syncthreads();
    for (int base = 0; base < NN; base += 1024) {
        int i = base + tid;
        int val = (i < NN) ? deg[i] : 0;
        int sc = val;
        #pragma unroll
        for (int off = 1; off < 64; off <<= 1) {
            int t = __shfl_up(sc, off);
            if (lane >= off) sc += t;
        }
        if (lane == 63) wsum[wid] = sc;
        __syncthreads();
        if (wid == 0 && lane < 16) {
            int t = wsum[lane];
            #pragma unroll
            for (int off = 1; off < 16; off <<= 1) {
                int uu = __shfl_up(t, off);
                if (lane >= off) t += uu;
            }
            wsum[lane] = t;
        }
        __syncthreads();
        int carry = carry_s;
        int wpre = wid ? wsum[wid - 1] : 0;
        int excl = carry + wpre + sc - val;
        if (i < NN) rowptr[i] = excl;
        __syncthreads();
        if (tid == 0) carry_s = carry + wsum[15];
    }
    if (tid == 0) rowptr[NN] = carry_s;
}

// -------- merged: csr_fill (atomic-free) | attn0 (layer-0 logits from x @ u) --------
__global__ __launch_bounds__(256) void fill_attn0(
    const int* __restrict__ ei, const int* __restrict__ rowptr,
    const int* __restrict__ erank, int* __restrict__ adj,
    const unsigned short* __restrict__ xb, const float* __restrict__ u,
    float* __restrict__ a_s, float* __restrict__ a_d)
{
    int tid = threadIdx.x;
    if (blockIdx.x < FB) {
        int e = blockIdx.x * 256 + tid;
        if (e >= ET) return;
        int s, d;
        if (e < EE) { s = ei[e]; d = ei[EE + e]; } else { s = d = e - EE; }
        adj[rowptr[d] + erank[e]] = s;
        return;
    }
    int t = (blockIdx.x - FB) * 256 + tid;
    if (t >= NN * 8) return;
    int n = t >> 3, h = t & 7;
    const uint4* xr = (const uint4*)(xb + (size_t)n * 128);
    float s = 0.f, dd = 0.f;
    #pragma unroll
    for (int q = 0; q < 16; q++) {        // 16 x uint4 = 128 channels
        uint4 raw = xr[q];
        unsigned vals[4] = {raw.x, raw.y, raw.z, raw.w};
        #pragma unroll
        for (int r = 0; r < 4; r++) {
            float lo, hi;
            unpack2(vals[r], lo, hi);
            int c = q * 8 + r * 2;
            s  += lo * u[c * 16 + h]     + hi * u[(c + 1) * 16 + h];
            dd += lo * u[c * 16 + 8 + h] + hi * u[(c + 1) * 16 + 8 + h];
        }
    }
    a_s[t] = s; a_d[t] = dd;
}

// ---------------- GEMM0: dual-output (xp | skip): A[MPAD][128] @ Wtc[512][128]^T ----
__global__ __launch_bounds__(256) void gemm0(
    const unsigned short* __restrict__ A, const unsigned short* __restrict__ Btc,
    unsigned short* __restrict__ C0, unsigned short* __restrict__ C1)
{
    __shared__ unsigned short As[128 * 64];
    const int K = 128;
    int tid = threadIdx.x;
    int rb = blockIdx.x * 128, cb = blockIdx.y * 128;
    int lane = tid & 63, wid = tid >> 6;
    int wm = (wid >> 1) * 64, wn = (wid & 1) * 64;
    int lr = lane & 15, lk = lane >> 4;
    f32x4 acc[4][4] = {};
    for (int kb = 0; kb < K; kb += 64) {
        #pragma unroll
        for (int i = 0; i < 4; i++) {
            int flat = tid + i * 256;
            int r = flat >> 3, c8 = flat & 7;
            int4 vv = *(const int4*)(A + (size_t)(rb + r) * K + kb + c8 * 8);
            *(int4*)(&As[r * 64 + ((c8 ^ (r & 7)) * 8)]) = vv;
        }
        __syncthreads();
        #pragma unroll
        for (int kk = 0; kk < 2; kk++) {
            int kbase = kb + kk * 32 + lk * 8;
            short8 bfr[4], afr[4];
            #pragma unroll
            for (int n = 0; n < 4; n++)
                bfr[n] = *(const short8*)(Btc + (size_t)(cb + wn + n * 16 + lr) * K + kbase);
            #pragma unroll
            for (int m = 0; m < 4; m++) {
                int row = wm + m * 16 + lr;
                int kchunk = kk * 4 + lk;
                afr[m] = *(const short8*)(&As[row * 64 + ((kchunk ^ (row & 7)) * 8)]);
            }
            #pragma unroll
            for (int m = 0; m < 4; m++)
                #pragma unroll
                for (int n = 0; n < 4; n++)
                    acc[m][n] = __builtin_amdgcn_mfma_f32_16x16x32_bf16(afr[m], bfr[n], acc[m][n], 0, 0, 0);
        }
        __syncthreads();
    }
    unsigned short* C = (cb < 256) ? C0 : C1;
    int cbase = cb & 255;
    #pragma unroll
    for (int m = 0; m < 4; m++)
        #pragma unroll
        for (int n = 0; n < 4; n++) {
            int col = cbase + wn + n * 16 + lr;
            #pragma unroll
            for (int j = 0; j < 4; j++) {
                int row = rb + wm + m * 16 + lk * 4 + j;
                C[(size_t)row * 256 + col] = f2bf(acc[m][n][j]);
            }
        }
}

// ---------------- GEMM1: xp1[MPAD][256] = h @ W1t^T (grid y=2) ----------------
__global__ __launch_bounds__(256) void gemm_bf16(
    const unsigned short* __restrict__ A, const unsigned short* __restrict__ Btc,
    unsigned short* __restrict__ C0, int K)
{
    __shared__ unsigned short As[128 * 64];
    int tid = threadIdx.x;
    int rb = blockIdx.x * 128, cb = blockIdx.y * 128;
    int lane = tid & 63, wid = tid >> 6;
    int wm = (wid >> 1) * 64, wn = (wid & 1) * 64;
    int lr = lane & 15, lk = lane >> 4;
    f32x4 acc[4][4] = {};
    for (int kb = 0; kb < K; kb += 64) {
        #pragma unroll
        for (int i = 0; i < 4; i++) {
            int flat = tid + i * 256;
            int r = flat >> 3, c8 = flat & 7;
            int4 vv = *(const int4*)(A + (size_t)(rb + r) * K + kb + c8 * 8);
            *(int4*)(&As[r * 64 + ((c8 ^ (r & 7)) * 8)]) = vv;
        }
        __syncthreads();
        #pragma unroll
        for (int kk = 0; kk < 2; kk++) {
            int kbase = kb + kk * 32 + lk * 8;
            short8 bfr[4], afr[4];
            #pragma unroll
            for (int n = 0; n < 4; n++)
                bfr[n] = *(const short8*)(Btc + (size_t)(cb + wn + n * 16 + lr) * K + kbase);
            #pragma unroll
            for (int m = 0; m < 4; m++) {
                int row = wm + m * 16 + lr;
                int kchunk = kk * 4 + lk;
                afr[m] = *(const short8*)(&As[row * 64 + ((kchunk ^ (row & 7)) * 8)]);
            }
            #pragma unroll
            for (int m = 0; m < 4; m++)
                #pragma unroll
                for (int n = 0; n < 4; n++)
                    acc[m][n] = __builtin_amdgcn_mfma_f32_16x16x32_bf16(afr[m], bfr[n], acc[m][n], 0, 0, 0);
        }
        __syncthreads();
    }
    #pragma unroll
    for (int m = 0; m < 4; m++)
        #pragma unroll
        for (int n = 0; n < 4; n++) {
            int col = cb + wn + n * 16 + lr;
            #pragma unroll
            for (int j = 0; j < 4; j++) {
                int row = rb + wm + m * 16 + lk * 4 + j;
                C0[(size_t)row * 256 + col] = f2bf(acc[m][n][j]);
            }
        }
}

// ---------------- gather0: half-wave edges, 8 ch/lane (R8-proven) ------------
__global__ __launch_bounds__(256) void gather0(
    const int* __restrict__ adj, const int* __restrict__ rowptr,
    const unsigned short* __restrict__ xp, const float* __restrict__ a_s,
    const float* __restrict__ a_d, unsigned short* __restrict__ out0)
{
    int w = (blockIdx.x * 256 + threadIdx.x) >> 6;
    int lane = threadIdx.x & 63;
    if (w >= NN) return;
    int hl = lane & 31;               // half-lane
    int hw = lane >> 5;               // which half-wave
    int h = hl >> 2;                  // head = (8*hl)/32
    float ad = a_d[w * 8 + h];
    int p = rowptr[w], end = rowptr[w + 1];
    unsigned loff = (unsigned)hl * 16u;
    float a0=0,a1=0,a2=0,a3=0,a4=0,a5=0,a6=0,a7=0;
    float b0=0,b1=0,b2=0,b3=0,b4=0,b5=0,b6=0,b7=0;
    float den0 = 0.f, den1 = 0.f;
    float lo, hi;
    for (; p + 4 <= end; p += 4) {
        int sA = adj[p + hw];
        int sB = adj[p + 2 + hw];
        float eA = a_s[sA * 8 + h] + ad;
        float eB = a_s[sB * 8 + h] + ad;
        float wA = __builtin_amdgcn_exp2f(fmaxf(eA, 0.2f * eA));
        float wB = __builtin_amdgcn_exp2f(fmaxf(eB, 0.2f * eB));
        uint4 rA = *(const uint4*)((const char*)xp + ((unsigned)sA * 512u + loff));
        uint4 rB = *(const uint4*)((const char*)xp + ((unsigned)sB * 512u + loff));
        den0 += wA; den1 += wB;
        unpack2(rA.x, lo, hi); a0 += wA * lo; a1 += wA * hi;
        unpack2(rA.y, lo, hi); a2 += wA * lo; a3 += wA * hi;
        unpack2(rA.z, lo, hi); a4 += wA * lo; a5 += wA * hi;
        unpack2(rA.w, lo, hi); a6 += wA * lo; a7 += wA * hi;
        unpack2(rB.x, lo, hi); b0 += wB * lo; b1 += wB * hi;
        unpack2(rB.y, lo, hi); b2 += wB * lo; b3 += wB * hi;
        unpack2(rB.z, lo, hi); b4 += wB * lo; b5 += wB * hi;
        unpack2(rB.w, lo, hi); b6 += wB * lo; b7 += wB * hi;
    }
    for (; p + 2 <= end; p += 2) {
        int sA = adj[p + hw];
        float eA = a_s[sA * 8 + h] + ad;
        float wA = __builtin_amdgcn_exp2f(fmaxf(eA, 0.2f * eA));
        uint4 rA = *(const uint4*)((const char*)xp + ((unsigned)sA * 512u + loff));
        den0 += wA;
        unpack2(rA.x, lo, hi); a0 += wA * lo; a1 += wA * hi;
        unpack2(rA.y, lo, hi); a2 += wA * lo; a3 += wA * hi;
        unpack2(rA.z, lo, hi); a4 += wA * lo; a5 += wA * hi;
        unpack2(rA.w, lo, hi); a6 += wA * lo; a7 += wA * hi;
    }
    if (p < end) {                     // single tail edge: half A only
        int sA = adj[p];
        float eA = a_s[sA * 8 + h] + ad;
        float wA = hw ? 0.f : __builtin_amdgcn_exp2f(fmaxf(eA, 0.2f * eA));
        uint4 rA = *(const uint4*)((const char*)xp + ((unsigned)sA * 512u + loff));
        den0 += wA;
        unpack2(rA.x, lo, hi); a0 += wA * lo; a1 += wA * hi;
        unpack2(rA.y, lo, hi); a2 += wA * lo; a3 += wA * hi;
        unpack2(rA.z, lo, hi); a4 += wA * lo; a5 += wA * hi;
        unpack2(rA.w, lo, hi); a6 += wA * lo; a7 += wA * hi;
    }
    a0 += b0; a1 += b1; a2 += b2; a3 += b3;
    a4 += b4; a5 += b5; a6 += b6; a7 += b7;
    float den = den0 + den1;
    den += __shfl_xor(den, 32);
    a0 += __shfl_xor(a0, 32); a1 += __shfl_xor(a1, 32);
    a2 += __shfl_xor(a2, 32); a3 += __shfl_xor(a3, 32);
    a4 += __shfl_xor(a4, 32); a5 += __shfl_xor(a5, 32);
    a6 += __shfl_xor(a6, 32); a7 += __shfl_xor(a7, 32);
    if (hw == 0) {
        float inv = 1.f / (den + 1e-16f);
        uint4 o;
        o.x = pack2(a0 * inv, a1 * inv);
        o.y = pack2(a2 * inv, a3 * inv);
        o.z = pack2(a4 * inv, a5 * inv);
        o.w = pack2(a6 * inv, a7 * inv);
        *(uint4*)((char*)out0 + ((size_t)w * 512u + loff)) = o;
    }
}

// ---------------- BN column stats (bf16 input) ----------------
__global__ __launch_bounds__(256) void bn_stats(
    const unsigned short* __restrict__ H, float* __restrict__ bnsum, float* __restrict__ bnsq)
{
    int c = threadIdx.x;
    int r0 = blockIdx.x * 64;
    float s = 0.f, sq = 0.f;
    for (int r = r0; r < r0 + 64; r++) {
        float val = bf2f(H[(size_t)r * 256 + c]);
        s += val; sq += val * val;
    }
    atomicAdd(&bnsum[c], s);
    atomicAdd(&bnsq[c], sq);
}

// ---------------- h = elu(bn(out0)) + skip ; fused layer-1 logits a1 = h @ v --------
__global__ __launch_bounds__(256) void bn_elu_attn(
    const unsigned short* __restrict__ out0, unsigned short* __restrict__ hb,
    const float* __restrict__ bnsum, const float* __restrict__ bnsq,
    const float* __restrict__ gamma, const float* __restrict__ beta,
    const float* __restrict__ bskip, const float* __restrict__ v,
    float* __restrict__ a_s, float* __restrict__ a_d)
{
    int i = blockIdx.x * 256 + threadIdx.x;   // one per 8 elems; 32 threads per row
    if (i >= MPAD * 32) return;
    int col0 = (i * 8) & 255;
    int row = i >> 5;
    uint4 hv = ((const uint4*)out0)[i];
    uint4 sv = ((const uint4*)hb)[i];
    float bn[8], sk[8];
    unpack2(hv.x, bn[0], bn[1]); unpack2(hv.y, bn[2], bn[3]);
    unpack2(hv.z, bn[4], bn[5]); unpack2(hv.w, bn[6], bn[7]);
    unpack2(sv.x, sk[0], sk[1]); unpack2(sv.y, sk[2], sk[3]);
    unpack2(sv.z, sk[4], sk[5]); unpack2(sv.w, sk[6], sk[7]);
    const float invN = 1.0f / (float)NN;
    float r[8];
    float ps = 0.f, pd = 0.f;
    #pragma unroll
    for (int q = 0; q < 8; q++) {
        int c = col0 + q;
        float mu = bnsum[c] * invN;
        float var = bnsq[c] * invN - mu * mu;
        float scl = rsqrtf(var + 1e-5f) * gamma[c];
        float b = (bn[q] - mu) * scl + beta[c];
        float el = b > 0.f ? b : (__expf(b) - 1.f);
        r[q] = el + sk[q] + bskip[c];
        float2 vv = *(const float2*)(v + c * 2);
        ps += r[q] * vv.x;
        pd += r[q] * vv.y;
    }
    uint4 o;
    o.x = pack2(r[0], r[1]); o.y = pack2(r[2], r[3]);
    o.z = pack2(r[4], r[5]); o.w = pack2(r[6], r[7]);
    ((uint4*)hb)[i] = o;
    #pragma unroll
    for (int off = 1; off < 32; off <<= 1) {
        ps += __shfl_xor(ps, off);
        pd += __shfl_xor(pd, off);
    }
    if ((threadIdx.x & 31) == 0 && row < NN) {
        a_s[row] = ps;
        a_d[row] = pd;
    }
}

// ---------------- gather1: half-wave edges (1 head), +b1, f32 out (R8-proven) -------
__global__ __launch_bounds__(256) void gather1(
    const int* __restrict__ adj, const int* __restrict__ rowptr,
    const unsigned short* __restrict__ xp, const float* __restrict__ a_s,
    const float* __restrict__ a_d, const float* __restrict__ b1,
    float* __restrict__ out)
{
    int w = (blockIdx.x * 256 + threadIdx.x) >> 6;
    int lane = threadIdx.x & 63;
    if (w >= NN) return;
    int hl = lane & 31;
    int hw = lane >> 5;
    float ad = a_d[w];
    int p = rowptr[w], end = rowptr[w + 1];
    unsigned loff = (unsigned)hl * 16u;
    float a0=0,a1=0,a2=0,a3=0,a4=0,a5=0,a6=0,a7=0;
    float b0s=0,b1s=0,b2s=0,b3s=0,b4s=0,b5s=0,b6s=0,b7s=0;
    float den0 = 0.f, den1 = 0.f;
    float lo, hi;
    for (; p + 4 <= end; p += 4) {
        int sA = adj[p + hw];
        int sB = adj[p + 2 + hw];
        float eA = a_s[sA] + ad;
        float eB = a_s[sB] + ad;
        float wA = __builtin_amdgcn_exp2f(fmaxf(eA, 0.2f * eA));
        float wB = __builtin_amdgcn_exp2f(fmaxf(eB, 0.2f * eB));
        uint4 rA = *(const uint4*)((const char*)xp + ((unsigned)sA * 512u + loff));
        uint4 rB = *(const uint4*)((const char*)xp + ((unsigned)sB * 512u + loff));
        den0 += wA; den1 += wB;
        unpack2(rA.x, lo, hi); a0 += wA * lo; a1 += wA * hi;
        unpack2(rA.y, lo, hi); a2 += wA * lo; a3 += wA * hi;
        unpack2(rA.z, lo, hi); a4 += wA * lo; a5 += wA * hi;
        unpack2(rA.w, lo, hi); a6 += wA * lo; a7 += wA * hi;
        unpack2(rB.x, lo, hi); b0s += wB * lo; b1s += wB * hi;
        unpack2(rB.y, lo, hi); b2s += wB * lo; b3s += wB * hi;
        unpack2(rB.z, lo, hi); b4s += wB * lo; b5s += wB * hi;
        unpack2(rB.w, lo, hi); b6s += wB * lo; b7s += wB * hi;
    }
    for (; p + 2 <= end; p += 2) {
        int sA = adj[p + hw];
        float eA = a_s[sA] + ad;
        float wA = __builtin_amdgcn_exp2f(fmaxf(eA, 0.2f * eA));
        uint4 rA = *(const uint4*)((const char*)xp + ((unsigned)sA * 512u + loff));
        den0 += wA;
        unpack2(rA.x, lo, hi); a0 += wA * lo; a1 += wA * hi;
        unpack2(rA.y, lo, hi); a2 += wA * lo; a3 += wA * hi;
        unpack2(rA.z, lo, hi); a4 += wA * lo; a5 += wA * hi;
        unpack2(rA.w, lo, hi); a6 += wA * lo; a7 += wA * hi;
    }
    if (p < end) {
        int sA = adj[p];
        float eA = a_s[sA] + ad;
        float wA = hw ? 0.f : __builtin_amdgcn_exp2f(fmaxf(eA, 0.2f * eA));
        uint4 rA = *(const uint4*)((const char*)xp + ((unsigned)sA * 512u + loff));
        den0 += wA;
        unpack2(rA.x, lo, hi); a0 += wA * lo; a1 += wA * hi;
        unpack2(rA.y, lo, hi); a2 += wA * lo; a3 += wA * hi;
        unpack2(rA.z, lo, hi); a4 += wA * lo; a5 += wA * hi;
        unpack2(rA.w, lo, hi); a6 += wA * lo; a7 += wA * hi;
    }
    a0 += b0s; a1 += b1s; a2 += b2s; a3 += b3s;
    a4 += b4s; a5 += b5s; a6 += b6s; a7 += b7s;
    float den = den0 + den1;
    den += __shfl_xor(den, 32);
    a0 += __shfl_xor(a0, 32); a1 += __shfl_xor(a1, 32);
    a2 += __shfl_xor(a2, 32); a3 += __shfl_xor(a3, 32);
    a4 += __shfl_xor(a4, 32); a5 += __shfl_xor(a5, 32);
    a6 += __shfl_xor(a6, 32); a7 += __shfl_xor(a7, 32);
    if (hw == 0) {
        float inv = 1.f / (den + 1e-16f);
        const float* bb = b1 + hl * 8;
        float4 o0 = {a0 * inv + bb[0], a1 * inv + bb[1],
                     a2 * inv + bb[2], a3 * inv + bb[3]};
        float4 o1 = {a4 * inv + bb[4], a5 * inv + bb[5],
                     a6 * inv + bb[6], a7 * inv + bb[7]};
        float* orow = out + (size_t)w * 256 + hl * 8;
        *(float4*)(orow) = o0;
        *(float4*)(orow + 4) = o1;
    }
}

extern "C" void kernel_launch(void* const* d_in, const int* in_sizes, int n_in,
                              void* d_out, int out_size, void* d_ws, size_t ws_size,
                              hipStream_t stream)
{
    const float* x      = (const float*)d_in[0];
    const int*   ei     = (const int*)d_in[1];
    const float* W0     = (const float*)d_in[2];
    const float* att_s0 = (const float*)d_in[3];
    const float* att_d0 = (const float*)d_in[4];
    // b0 (d_in[5]) cancels under BatchNorm -> unused
    const float* gamma0 = (const float*)d_in[6];
    const float* beta0  = (const float*)d_in[7];
    const float* W_skip = (const float*)d_in[8];
    const float* b_skip = (const float*)d_in[9];
    const float* W1     = (const float*)d_in[10];
    const float* att_s1 = (const float*)d_in[11];
    const float* att_d1 = (const float*)d_in[12];
    const float* b1     = (const float*)d_in[13];
    float* out = (float*)d_out;

    // workspace layout (deg..bnsq contiguous for single memset)
    char* p = (char*)d_ws;
    unsigned short* x_bf  = (unsigned short*)p; p += (size_t)MPAD * 128 * 2;
    unsigned short* xp_bf = (unsigned short*)p; p += (size_t)MPAD * 256 * 2;  // xp0 then xp1
    unsigned short* h_bf  = (unsigned short*)p; p += (size_t)MPAD * 256 * 2;  // skip, then h in place
    unsigned short* out0b = (unsigned short*)p; p += (size_t)MPAD * 256 * 2;
    unsigned short* Wtc   = (unsigned short*)p; p += (size_t)512 * 128 * 2;   // [W0t | Wst]
    unsigned short* W1t   = (unsigned short*)p; p += (size_t)256 * 256 * 2;
    float* v     = (float*)p; p += 512 * 4;
    float* u     = (float*)p; p += 2048 * 4;
    float* a_s   = (float*)p; p += (size_t)NN * 8 * 4;
    float* a_d   = (float*)p; p += (size_t)NN * 8 * 4;
    int*   deg   = (int*)p;   p += (size_t)NN * 4;
    float* bnsum = (float*)p; p += 256 * 4;
    float* bnsq  = (float*)p; p += 256 * 4;
    int* rowptr = (int*)p; p += (size_t)(NN + 1) * 4;
    int* erank  = (int*)p; p += (size_t)ET * 4;
    int* adj    = (int*)p; p += (size_t)ET * 4;

    // one memset covers deg + bnsum + bnsq (contiguous)
    hipMemsetAsync(deg, 0, (size_t)(NN + 512) * 4, stream);
    // deterministic pad rows for out0b (never written by gather0)
    hipMemsetAsync(out0b + (size_t)NN * 256, 0, (size_t)(MPAD - NN) * 256 * 2, stream);

    // phase 1: converts + u/v projections + csr_count(+rank) (one kernel)
    prep<<<(PREP_TOTAL + 255) / 256, 256, 0, stream>>>(
        x, W0, W_skip, W1, att_s0, att_d0, att_s1, att_d1, ei,
        x_bf, Wtc, W1t, v, u, deg, erank);

    // phase 2: exscan
    exscan<<<1, 1024, 0, stream>>>(deg, rowptr);

    // phase 3: csr_fill | layer-0 logits (merged, both low-resource)
    fill_attn0<<<FB + AB, 256, 0, stream>>>(ei, rowptr, erank, adj, x_bf, u, a_s, a_d);

    // phase 4: GEMM0 (dual output xp | skip)
    dim3 gg0(MPAD / 128, 4);
    gemm0<<<gg0, 256, 0, stream>>>(x_bf, Wtc, xp_bf, h_bf);

    // phase 5: gather0
    gather0<<<(NN * 64 + 255) / 256, 256, 0, stream>>>(adj, rowptr, xp_bf, a_s, a_d, out0b);

    // phase 6: BN stats
    bn_stats<<<NN / 64, 256, 0, stream>>>(out0b, bnsum, bnsq);

    // phase 7: BN + ELU + skip, fused layer-1 logits
    bn_elu_attn<<<(MPAD * 32 + 255) / 256, 256, 0, stream>>>(
        out0b, h_bf, bnsum, bnsq, gamma0, beta0, b_skip, v, a_s, a_d);

    // phase 8: GEMM1
    dim3 gg1(MPAD / 128, 2);
    gemm_bf16<<<gg1, 256, 0, stream>>>(h_bf, W1t, xp_bf, 256);

    // phase 9: gather1
    gather1<<<(NN * 64 + 255) / 256, 256, 0, stream>>>(adj, rowptr, xp_bf, a_s, a_d, b1, out);
}

// Round 18
// 285.416 us; speedup vs baseline: 1.0142x; 1.0098x over previous
//
#include <hip/hip_runtime.h>
#include <hip/hip_bf16.h>

#define NN 40000
#define EE 640000
#define ET 680000   // EE + NN self loops
#define MPAD 40064  // 313 * 128
#define LOG2E 1.4426950408889634f

// prep kernel index ranges
#define XN (MPAD * 128 / 4)          // conv_x items (4 elems each)
#define WN 131072                    // weight transpose items
#define VN 512                       // v projection items (layer-1 logit vectors)
#define UN 2048                      // u projection items (layer-0 logit vectors)
#define PREP_TOTAL (XN + WN + VN + UN + ET)

// fill_attn0 block ranges
#define FB ((ET + 255) / 256)        // csr_fill blocks
#define AB ((NN * 8 + 255) / 256)    // attn0 blocks

#if __has_builtin(__builtin_amdgcn_global_load_lds)
#define USE_GLDS 1
typedef const __attribute__((address_space(1))) unsigned int* gas_ptr;
typedef __attribute__((address_space(3))) unsigned int* las_ptr;
#else
#define USE_GLDS 0
#endif

typedef __attribute__((ext_vector_type(8))) short short8;
typedef __attribute__((ext_vector_type(4))) float f32x4;

__device__ __forceinline__ float bf2f(unsigned u) {
    return __uint_as_float(u << 16);
}
__device__ __forceinline__ unsigned short f2bf(float f) {
    unsigned u = __float_as_uint(f);
    return (unsigned short)((u + 0x7FFFu + ((u >> 16) & 1u)) >> 16);
}
__device__ __forceinline__ unsigned pack2(float lo, float hi) {
    return ((unsigned)f2bf(lo)) | (((unsigned)f2bf(hi)) << 16);
}
__device__ __forceinline__ void unpack2(unsigned u, float& lo, float& hi) {
    lo = __uint_as_float(u << 16);
    hi = __uint_as_float(u & 0xffff0000u);
}

// A-tile staging: LDS slot s holds global chunk s^(r&7)  (XOR involution,
// same layout as the old swizzled write; reads unchanged).
__device__ __forceinline__ void stage_a(
    const unsigned short* __restrict__ A, unsigned short* As,
    int rb, int kb, int K, int tid)
{
    #pragma unroll
    for (int i = 0; i < 4; i++) {
        int flat = tid + i * 256;
        int r = flat >> 3, s = flat & 7;
        int c8 = s ^ (r & 7);
        const unsigned short* src = A + (size_t)(rb + r) * K + kb + c8 * 8;
#if USE_GLDS
        __builtin_amdgcn_global_load_lds((gas_ptr)src, (las_ptr)(&As[flat * 8]), 16, 0, 0);
#else
        *(int4*)(&As[flat * 8]) = *(const int4*)src;
#endif
    }
}

// -- prep: conv_x | weight transposes | v proj | u proj | csr_count(+edge rank) --
__global__ __launch_bounds__(256) void prep(
    const float* __restrict__ x, const float* __restrict__ W0,
    const float* __restrict__ Ws, const float* __restrict__ W1,
    const float* __restrict__ as0, const float* __restrict__ ad0,
    const float* __restrict__ as1, const float* __restrict__ ad1,
    const int* __restrict__ ei,
    unsigned short* __restrict__ xb, unsigned short* __restrict__ Wtc,
    unsigned short* __restrict__ W1t, float* __restrict__ v, float* __restrict__ u,
    int* __restrict__ deg, int* __restrict__ erank)
{
    int i = blockIdx.x * 256 + threadIdx.x;
    if (i < XN) {
        int row = (i * 4) >> 7;
        ushort4 o;
        if (row < NN) {
            float4 val = ((const float4*)x)[i];
            o.x = f2bf(val.x); o.y = f2bf(val.y); o.z = f2bf(val.z); o.w = f2bf(val.w);
        } else { o.x = o.y = o.z = o.w = 0; }
        ((ushort4*)xb)[i] = o;
    } else if (i < XN + WN) {
        int j = i - XN;
        if (j < 32768) {
            int c = j >> 7, k = j & 127;
            Wtc[j] = f2bf(W0[(size_t)k * 256 + c]);
        } else if (j < 65536) {
            int jj = j - 32768;
            int c = jj >> 7, k = jj & 127;
            Wtc[j] = f2bf(Ws[(size_t)k * 256 + c]);
        } else {
            int jj = j - 65536;
            int c = jj >> 8, k = jj & 255;
            W1t[jj] = f2bf(W1[(size_t)k * 256 + c]);
        }
    } else if (i < XN + WN + VN) {
        int j = i - XN - WN;         // [0,512)
        int k = j >> 1, which = j & 1;
        const float* att = which ? ad1 : as1;
        float sum = 0.f;
        for (int c = 0; c < 256; c++)
            sum += W1[(size_t)k * 256 + c] * att[c];
        v[j] = sum * LOG2E;
    } else if (i < XN + WN + VN + UN) {
        int j = i - XN - WN - VN;    // [0,2048): k = j>>4, jj = j&15
        int k = j >> 4, jj = j & 15;
        int h = jj & 7;
        const float* att = (jj < 8) ? as0 : ad0;
        float sum = 0.f;
        #pragma unroll
        for (int c = 0; c < 32; c++)
            sum += W0[(size_t)k * 256 + h * 32 + c] * att[h * 32 + c];
        u[j] = sum * LOG2E;
    } else {
        int e = i - XN - WN - VN - UN;
        if (e < ET) {
            int d = (e < EE) ? ei[EE + e] : (e - EE);
            erank[e] = atomicAdd(&deg[d], 1);   // rank within dst row
        }
    }
}

// ---------------- exscan (single block, shfl-based) ----------------
__global__ __launch_bounds__(1024) void exscan(
    const int* __restrict__ deg, int* __restrict__ rowptr)
{
    __shared__ int wsum[16];
    __shared__ int carry_s;
    int tid = threadIdx.x, lane = tid & 63, wid = tid >> 6;
    if (tid == 0) carry_s = 0;
    __syncthreads();
    for (int base = 0; base < NN; base += 1024) {
        int i = base + tid;
        int val = (i < NN) ? deg[i] : 0;
        int sc = val;
        #pragma unroll
        for (int off = 1; off < 64; off <<= 1) {
            int t = __shfl_up(sc, off);
            if (lane >= off) sc += t;
        }
        if (lane == 63) wsum[wid] = sc;
        __syncthreads();
        if (wid == 0 && lane < 16) {
            int t = wsum[lane];
            #pragma unroll
            for (int off = 1; off < 16; off <<= 1) {
                int uu = __shfl_up(t, off);
                if (lane >= off) t += uu;
            }
            wsum[lane] = t;
        }
        __syncthreads();
        int carry = carry_s;
        int wpre = wid ? wsum[wid - 1] : 0;
        int excl = carry + wpre + sc - val;
        if (i < NN) rowptr[i] = excl;
        __syncthreads();
        if (tid == 0) carry_s = carry + wsum[15];
    }
    if (tid == 0) rowptr[NN] = carry_s;
}

// -------- merged: csr_fill (atomic-free) | attn0 (layer-0 logits from x @ u) --------
__global__ __launch_bounds__(256) void fill_attn0(
    const int* __restrict__ ei, const int* __restrict__ rowptr,
    const int* __restrict__ erank, int* __restrict__ adj,
    const unsigned short* __restrict__ xb, const float* __restrict__ u,
    float* __restrict__ a_s, float* __restrict__ a_d)
{
    int tid = threadIdx.x;
    if (blockIdx.x < FB) {
        int e = blockIdx.x * 256 + tid;
        if (e >= ET) return;
        int s, d;
        if (e < EE) { s = ei[e]; d = ei[EE + e]; } else { s = d = e - EE; }
        adj[rowptr[d] + erank[e]] = s;
        return;
    }
    int t = (blockIdx.x - FB) * 256 + tid;
    if (t >= NN * 8) return;
    int n = t >> 3, h = t & 7;
    const uint4* xr = (const uint4*)(xb + (size_t)n * 128);
    float s = 0.f, dd = 0.f;
    #pragma unroll
    for (int q = 0; q < 16; q++) {        // 16 x uint4 = 128 channels
        uint4 raw = xr[q];
        unsigned vals[4] = {raw.x, raw.y, raw.z, raw.w};
        #pragma unroll
        for (int r = 0; r < 4; r++) {
            float lo, hi;
            unpack2(vals[r], lo, hi);
            int c = q * 8 + r * 2;
            s  += lo * u[c * 16 + h]     + hi * u[(c + 1) * 16 + h];
            dd += lo * u[c * 16 + 8 + h] + hi * u[(c + 1) * 16 + 8 + h];
        }
    }
    a_s[t] = s; a_d[t] = dd;
}

// ---------------- GEMM0: dual-output (xp | skip): A[MPAD][128] @ Wtc[512][128]^T ----
__global__ __launch_bounds__(256) void gemm0(
    const unsigned short* __restrict__ A, const unsigned short* __restrict__ Btc,
    unsigned short* __restrict__ C0, unsigned short* __restrict__ C1)
{
    __shared__ unsigned short As[128 * 64];
    const int K = 128;
    int tid = threadIdx.x;
    int rb = blockIdx.x * 128, cb = blockIdx.y * 128;
    int lane = tid & 63, wid = tid >> 6;
    int wm = (wid >> 1) * 64, wn = (wid & 1) * 64;
    int lr = lane & 15, lk = lane >> 4;
    f32x4 acc[4][4] = {};
    for (int kb = 0; kb < K; kb += 64) {
        stage_a(A, As, rb, kb, K, tid);
        __syncthreads();
        #pragma unroll
        for (int kk = 0; kk < 2; kk++) {
            int kbase = kb + kk * 32 + lk * 8;
            short8 bfr[4], afr[4];
            #pragma unroll
            for (int n = 0; n < 4; n++)
                bfr[n] = *(const short8*)(Btc + (size_t)(cb + wn + n * 16 + lr) * K + kbase);
            #pragma unroll
            for (int m = 0; m < 4; m++) {
                int row = wm + m * 16 + lr;
                int kchunk = kk * 4 + lk;
                afr[m] = *(const short8*)(&As[row * 64 + ((kchunk ^ (row & 7)) * 8)]);
            }
            #pragma unroll
            for (int m = 0; m < 4; m++)
                #pragma unroll
                for (int n = 0; n < 4; n++)
                    acc[m][n] = __builtin_amdgcn_mfma_f32_16x16x32_bf16(afr[m], bfr[n], acc[m][n], 0, 0, 0);
        }
        __syncthreads();
    }
    unsigned short* C = (cb < 256) ? C0 : C1;
    int cbase = cb & 255;
    #pragma unroll
    for (int m = 0; m < 4; m++)
        #pragma unroll
        for (int n = 0; n < 4; n++) {
            int col = cbase + wn + n * 16 + lr;
            #pragma unroll
            for (int j = 0; j < 4; j++) {
                int row = rb + wm + m * 16 + lk * 4 + j;
                C[(size_t)row * 256 + col] = f2bf(acc[m][n][j]);
            }
        }
}

// ---------------- GEMM1: xp1[MPAD][256] = h @ W1t^T (grid y=2) ----------------
__global__ __launch_bounds__(256) void gemm_bf16(
    const unsigned short* __restrict__ A, const unsigned short* __restrict__ Btc,
    unsigned short* __restrict__ C0, int K)
{
    __shared__ unsigned short As[128 * 64];
    int tid = threadIdx.x;
    int rb = blockIdx.x * 128, cb = blockIdx.y * 128;
    int lane = tid & 63, wid = tid >> 6;
    int wm = (wid >> 1) * 64, wn = (wid & 1) * 64;
    int lr = lane & 15, lk = lane >> 4;
    f32x4 acc[4][4] = {};
    for (int kb = 0; kb < K; kb += 64) {
        stage_a(A, As, rb, kb, K, tid);
        __syncthreads();
        #pragma unroll
        for (int kk = 0; kk < 2; kk++) {
            int kbase = kb + kk * 32 + lk * 8;
            short8 bfr[4], afr[4];
            #pragma unroll
            for (int n = 0; n < 4; n++)
                bfr[n] = *(const short8*)(Btc + (size_t)(cb + wn + n * 16 + lr) * K + kbase);
            #pragma unroll
            for (int m = 0; m < 4; m++) {
                int row = wm + m * 16 + lr;
                int kchunk = kk * 4 + lk;
                afr[m] = *(const short8*)(&As[row * 64 + ((kchunk ^ (row & 7)) * 8)]);
            }
            #pragma unroll
            for (int m = 0; m < 4; m++)
                #pragma unroll
                for (int n = 0; n < 4; n++)
                    acc[m][n] = __builtin_amdgcn_mfma_f32_16x16x32_bf16(afr[m], bfr[n], acc[m][n], 0, 0, 0);
        }
        __syncthreads();
    }
    #pragma unroll
    for (int m = 0; m < 4; m++)
        #pragma unroll
        for (int n = 0; n < 4; n++) {
            int col = cb + wn + n * 16 + lr;
            #pragma unroll
            for (int j = 0; j < 4; j++) {
                int row = rb + wm + m * 16 + lk * 4 + j;
                C0[(size_t)row * 256 + col] = f2bf(acc[m][n][j]);
            }
        }
}

// ---------------- gather0: half-wave edges, 8 ch/lane (R8-proven) ------------
__global__ __launch_bounds__(256) void gather0(
    const int* __restrict__ adj, const int* __restrict__ rowptr,
    const unsigned short* __restrict__ xp, const float* __restrict__ a_s,
    const float* __restrict__ a_d, unsigned short* __restrict__ out0)
{
    int w = (blockIdx.x * 256 + threadIdx.x) >> 6;
    int lane = threadIdx.x & 63;
    if (w >= NN) return;
    int hl = lane & 31;               // half-lane
    int hw = lane >> 5;               // which half-wave
    int h = hl >> 2;                  // head = (8*hl)/32
    float ad = a_d[w * 8 + h];
    int p = rowptr[w], end = rowptr[w + 1];
    unsigned loff = (unsigned)hl * 16u;
    float a0=0,a1=0,a2=0,a3=0,a4=0,a5=0,a6=0,a7=0;
    float b0=0,b1=0,b2=0,b3=0,b4=0,b5=0,b6=0,b7=0;
    float den0 = 0.f, den1 = 0.f;
    float lo, hi;
    for (; p + 4 <= end; p += 4) {
        int sA = adj[p + hw];
        int sB = adj[p + 2 + hw];
        float eA = a_s[sA * 8 + h] + ad;
        float eB = a_s[sB * 8 + h] + ad;
        float wA = __builtin_amdgcn_exp2f(fmaxf(eA, 0.2f * eA));
        float wB = __builtin_amdgcn_exp2f(fmaxf(eB, 0.2f * eB));
        uint4 rA = *(const uint4*)((const char*)xp + ((unsigned)sA * 512u + loff));
        uint4 rB = *(const uint4*)((const char*)xp + ((unsigned)sB * 512u + loff));
        den0 += wA; den1 += wB;
        unpack2(rA.x, lo, hi); a0 += wA * lo; a1 += wA * hi;
        unpack2(rA.y, lo, hi); a2 += wA * lo; a3 += wA * hi;
        unpack2(rA.z, lo, hi); a4 += wA * lo; a5 += wA * hi;
        unpack2(rA.w, lo, hi); a6 += wA * lo; a7 += wA * hi;
        unpack2(rB.x, lo, hi); b0 += wB * lo; b1 += wB * hi;
        unpack2(rB.y, lo, hi); b2 += wB * lo; b3 += wB * hi;
        unpack2(rB.z, lo, hi); b4 += wB * lo; b5 += wB * hi;
        unpack2(rB.w, lo, hi); b6 += wB * lo; b7 += wB * hi;
    }
    for (; p + 2 <= end; p += 2) {
        int sA = adj[p + hw];
        float eA = a_s[sA * 8 + h] + ad;
        float wA = __builtin_amdgcn_exp2f(fmaxf(eA, 0.2f * eA));
        uint4 rA = *(const uint4*)((const char*)xp + ((unsigned)sA * 512u + loff));
        den0 += wA;
        unpack2(rA.x, lo, hi); a0 += wA * lo; a1 += wA * hi;
        unpack2(rA.y, lo, hi); a2 += wA * lo; a3 += wA * hi;
        unpack2(rA.z, lo, hi); a4 += wA * lo; a5 += wA * hi;
        unpack2(rA.w, lo, hi); a6 += wA * lo; a7 += wA * hi;
    }
    if (p < end) {                     // single tail edge: half A only
        int sA = adj[p];
        float eA = a_s[sA * 8 + h] + ad;
        float wA = hw ? 0.f : __builtin_amdgcn_exp2f(fmaxf(eA, 0.2f * eA));
        uint4 rA = *(const uint4*)((const char*)xp + ((unsigned)sA * 512u + loff));
        den0 += wA;
        unpack2(rA.x, lo, hi); a0 += wA * lo; a1 += wA * hi;
        unpack2(rA.y, lo, hi); a2 += wA * lo; a3 += wA * hi;
        unpack2(rA.z, lo, hi); a4 += wA * lo; a5 += wA * hi;
        unpack2(rA.w, lo, hi); a6 += wA * lo; a7 += wA * hi;
    }
    a0 += b0; a1 += b1; a2 += b2; a3 += b3;
    a4 += b4; a5 += b5; a6 += b6; a7 += b7;
    float den = den0 + den1;
    den += __shfl_xor(den, 32);
    a0 += __shfl_xor(a0, 32); a1 += __shfl_xor(a1, 32);
    a2 += __shfl_xor(a2, 32); a3 += __shfl_xor(a3, 32);
    a4 += __shfl_xor(a4, 32); a5 += __shfl_xor(a5, 32);
    a6 += __shfl_xor(a6, 32); a7 += __shfl_xor(a7, 32);
    if (hw == 0) {
        float inv = 1.f / (den + 1e-16f);
        uint4 o;
        o.x = pack2(a0 * inv, a1 * inv);
        o.y = pack2(a2 * inv, a3 * inv);
        o.z = pack2(a4 * inv, a5 * inv);
        o.w = pack2(a6 * inv, a7 * inv);
        *(uint4*)((char*)out0 + ((size_t)w * 512u + loff)) = o;
    }
}

// ---------------- BN column stats (bf16 input) ----------------
__global__ __launch_bounds__(256) void bn_stats(
    const unsigned short* __restrict__ H, float* __restrict__ bnsum, float* __restrict__ bnsq)
{
    int c = threadIdx.x;
    int r0 = blockIdx.x * 64;
    float s = 0.f, sq = 0.f;
    for (int r = r0; r < r0 + 64; r++) {
        float val = bf2f(H[(size_t)r * 256 + c]);
        s += val; sq += val * val;
    }
    atomicAdd(&bnsum[c], s);
    atomicAdd(&bnsq[c], sq);
}

// ---------------- h = elu(bn(out0)) + skip ; fused layer-1 logits a1 = h @ v --------
__global__ __launch_bounds__(256) void bn_elu_attn(
    const unsigned short* __restrict__ out0, unsigned short* __restrict__ hb,
    const float* __restrict__ bnsum, const float* __restrict__ bnsq,
    const float* __restrict__ gamma, const float* __restrict__ beta,
    const float* __restrict__ bskip, const float* __restrict__ v,
    float* __restrict__ a_s, float* __restrict__ a_d)
{
    int i = blockIdx.x * 256 + threadIdx.x;   // one per 8 elems; 32 threads per row
    if (i >= MPAD * 32) return;
    int col0 = (i * 8) & 255;
    int row = i >> 5;
    uint4 hv = ((const uint4*)out0)[i];
    uint4 sv = ((const uint4*)hb)[i];
    float bn[8], sk[8];
    unpack2(hv.x, bn[0], bn[1]); unpack2(hv.y, bn[2], bn[3]);
    unpack2(hv.z, bn[4], bn[5]); unpack2(hv.w, bn[6], bn[7]);
    unpack2(sv.x, sk[0], sk[1]); unpack2(sv.y, sk[2], sk[3]);
    unpack2(sv.z, sk[4], sk[5]); unpack2(sv.w, sk[6], sk[7]);
    const float invN = 1.0f / (float)NN;
    float r[8];
    float ps = 0.f, pd = 0.f;
    #pragma unroll
    for (int q = 0; q < 8; q++) {
        int c = col0 + q;
        float mu = bnsum[c] * invN;
        float var = bnsq[c] * invN - mu * mu;
        float scl = rsqrtf(var + 1e-5f) * gamma[c];
        float b = (bn[q] - mu) * scl + beta[c];
        float el = b > 0.f ? b : (__expf(b) - 1.f);
        r[q] = el + sk[q] + bskip[c];
        float2 vv = *(const float2*)(v + c * 2);
        ps += r[q] * vv.x;
        pd += r[q] * vv.y;
    }
    uint4 o;
    o.x = pack2(r[0], r[1]); o.y = pack2(r[2], r[3]);
    o.z = pack2(r[4], r[5]); o.w = pack2(r[6], r[7]);
    ((uint4*)hb)[i] = o;
    #pragma unroll
    for (int off = 1; off < 32; off <<= 1) {
        ps += __shfl_xor(ps, off);
        pd += __shfl_xor(pd, off);
    }
    if ((threadIdx.x & 31) == 0 && row < NN) {
        a_s[row] = ps;
        a_d[row] = pd;
    }
}

// ---------------- gather1: half-wave edges (1 head), +b1, f32 out (R8-proven) -------
__global__ __launch_bounds__(256) void gather1(
    const int* __restrict__ adj, const int* __restrict__ rowptr,
    const unsigned short* __restrict__ xp, const float* __restrict__ a_s,
    const float* __restrict__ a_d, const float* __restrict__ b1,
    float* __restrict__ out)
{
    int w = (blockIdx.x * 256 + threadIdx.x) >> 6;
    int lane = threadIdx.x & 63;
    if (w >= NN) return;
    int hl = lane & 31;
    int hw = lane >> 5;
    float ad = a_d[w];
    int p = rowptr[w], end = rowptr[w + 1];
    unsigned loff = (unsigned)hl * 16u;
    float a0=0,a1=0,a2=0,a3=0,a4=0,a5=0,a6=0,a7=0;
    float b0s=0,b1s=0,b2s=0,b3s=0,b4s=0,b5s=0,b6s=0,b7s=0;
    float den0 = 0.f, den1 = 0.f;
    float lo, hi;
    for (; p + 4 <= end; p += 4) {
        int sA = adj[p + hw];
        int sB = adj[p + 2 + hw];
        float eA = a_s[sA] + ad;
        float eB = a_s[sB] + ad;
        float wA = __builtin_amdgcn_exp2f(fmaxf(eA, 0.2f * eA));
        float wB = __builtin_amdgcn_exp2f(fmaxf(eB, 0.2f * eB));
        uint4 rA = *(const uint4*)((const char*)xp + ((unsigned)sA * 512u + loff));
        uint4 rB = *(const uint4*)((const char*)xp + ((unsigned)sB * 512u + loff));
        den0 += wA; den1 += wB;
        unpack2(rA.x, lo, hi); a0 += wA * lo; a1 += wA * hi;
        unpack2(rA.y, lo, hi); a2 += wA * lo; a3 += wA * hi;
        unpack2(rA.z, lo, hi); a4 += wA * lo; a5 += wA * hi;
        unpack2(rA.w, lo, hi); a6 += wA * lo; a7 += wA * hi;
        unpack2(rB.x, lo, hi); b0s += wB * lo; b1s += wB * hi;
        unpack2(rB.y, lo, hi); b2s += wB * lo; b3s += wB * hi;
        unpack2(rB.z, lo, hi); b4s += wB * lo; b5s += wB * hi;
        unpack2(rB.w, lo, hi); b6s += wB * lo; b7s += wB * hi;
    }
    for (; p + 2 <= end; p += 2) {
        int sA = adj[p + hw];
        float eA = a_s[sA] + ad;
        float wA = __builtin_amdgcn_exp2f(fmaxf(eA, 0.2f * eA));
        uint4 rA = *(const uint4*)((const char*)xp + ((unsigned)sA * 512u + loff));
        den0 += wA;
        unpack2(rA.x, lo, hi); a0 += wA * lo; a1 += wA * hi;
        unpack2(rA.y, lo, hi); a2 += wA * lo; a3 += wA * hi;
        unpack2(rA.z, lo, hi); a4 += wA * lo; a5 += wA * hi;
        unpack2(rA.w, lo, hi); a6 += wA * lo; a7 += wA * hi;
    }
    if (p < end) {
        int sA = adj[p];
        float eA = a_s[sA] + ad;
        float wA = hw ? 0.f : __builtin_amdgcn_exp2f(fmaxf(eA, 0.2f * eA));
        uint4 rA = *(const uint4*)((const char*)xp + ((unsigned)sA * 512u + loff));
        den0 += wA;
        unpack2(rA.x, lo, hi); a0 += wA * lo; a1 += wA * hi;
        unpack2(rA.y, lo, hi); a2 += wA * lo; a3 += wA * hi;
        unpack2(rA.z, lo, hi); a4 += wA * lo; a5 += wA * hi;
        unpack2(rA.w, lo, hi); a6 += wA * lo; a7 += wA * hi;
    }
    a0 += b0s; a1 += b1s; a2 += b2s; a3 += b3s;
    a4 += b4s; a5 += b5s; a6 += b6s; a7 += b7s;
    float den = den0 + den1;
    den += __shfl_xor(den, 32);
    a0 += __shfl_xor(a0, 32); a1 += __shfl_xor(a1, 32);
    a2 += __shfl_xor(a2, 32); a3 += __shfl_xor(a3, 32);
    a4 += __shfl_xor(a4, 32); a5 += __shfl_xor(a5, 32);
    a6 += __shfl_xor(a6, 32); a7 += __shfl_xor(a7, 32);
    if (hw == 0) {
        float inv = 1.f / (den + 1e-16f);
        const float* bb = b1 + hl * 8;
        float4 o0 = {a0 * inv + bb[0], a1 * inv + bb[1],
                     a2 * inv + bb[2], a3 * inv + bb[3]};
        float4 o1 = {a4 * inv + bb[4], a5 * inv + bb[5],
                     a6 * inv + bb[6], a7 * inv + bb[7]};
        float* orow = out + (size_t)w * 256 + hl * 8;
        *(float4*)(orow) = o0;
        *(float4*)(orow + 4) = o1;
    }
}

extern "C" void kernel_launch(void* const* d_in, const int* in_sizes, int n_in,
                              void* d_out, int out_size, void* d_ws, size_t ws_size,
                              hipStream_t stream)
{
    const float* x      = (const float*)d_in[0];
    const int*   ei     = (const int*)d_in[1];
    const float* W0     = (const float*)d_in[2];
    const float* att_s0 = (const float*)d_in[3];
    const float* att_d0 = (const float*)d_in[4];
    // b0 (d_in[5]) cancels under BatchNorm -> unused
    const float* gamma0 = (const float*)d_in[6];
    const float* beta0  = (const float*)d_in[7];
    const float* W_skip = (const float*)d_in[8];
    const float* b_skip = (const float*)d_in[9];
    const float* W1     = (const float*)d_in[10];
    const float* att_s1 = (const float*)d_in[11];
    const float* att_d1 = (const float*)d_in[12];
    const float* b1     = (const float*)d_in[13];
    float* out = (float*)d_out;

    // workspace layout (deg..bnsq contiguous for single memset)
    char* p = (char*)d_ws;
    unsigned short* x_bf  = (unsigned short*)p; p += (size_t)MPAD * 128 * 2;
    unsigned short* xp_bf = (unsigned short*)p; p += (size_t)MPAD * 256 * 2;  // xp0 then xp1
    unsigned short* h_bf  = (unsigned short*)p; p += (size_t)MPAD * 256 * 2;  // skip, then h in place
    unsigned short* out0b = (unsigned short*)p; p += (size_t)MPAD * 256 * 2;
    unsigned short* Wtc   = (unsigned short*)p; p += (size_t)512 * 128 * 2;   // [W0t | Wst]
    unsigned short* W1t   = (unsigned short*)p; p += (size_t)256 * 256 * 2;
    float* v     = (float*)p; p += 512 * 4;
    float* u     = (float*)p; p += 2048 * 4;
    float* a_s   = (float*)p; p += (size_t)NN * 8 * 4;
    float* a_d   = (float*)p; p += (size_t)NN * 8 * 4;
    int*   deg   = (int*)p;   p += (size_t)NN * 4;
    float* bnsum = (float*)p; p += 256 * 4;
    float* bnsq  = (float*)p; p += 256 * 4;
    int* rowptr = (int*)p; p += (size_t)(NN + 1) * 4;
    int* erank  = (int*)p; p += (size_t)ET * 4;
    int* adj    = (int*)p; p += (size_t)ET * 4;

    // one memset covers deg + bnsum + bnsq (contiguous)
    hipMemsetAsync(deg, 0, (size_t)(NN + 512) * 4, stream);
    // deterministic pad rows for out0b (never written by gather0)
    hipMemsetAsync(out0b + (size_t)NN * 256, 0, (size_t)(MPAD - NN) * 256 * 2, stream);

    // phase 1: converts + u/v projections + csr_count(+rank) (one kernel)
    prep<<<(PREP_TOTAL + 255) / 256, 256, 0, stream>>>(
        x, W0, W_skip, W1, att_s0, att_d0, att_s1, att_d1, ei,
        x_bf, Wtc, W1t, v, u, deg, erank);

    // phase 2: exscan
    exscan<<<1, 1024, 0, stream>>>(deg, rowptr);

    // phase 3: csr_fill | layer-0 logits (merged, both low-resource)
    fill_attn0<<<FB + AB, 256, 0, stream>>>(ei, rowptr, erank, adj, x_bf, u, a_s, a_d);

    // phase 4: GEMM0 (dual output xp | skip)
    dim3 gg0(MPAD / 128, 4);
    gemm0<<<gg0, 256, 0, stream>>>(x_bf, Wtc, xp_bf, h_bf);

    // phase 5: gather0
    gather0<<<(NN * 64 + 255) / 256, 256, 0, stream>>>(adj, rowptr, xp_bf, a_s, a_d, out0b);

    // phase 6: BN stats
    bn_stats<<<NN / 64, 256, 0, stream>>>(out0b, bnsum, bnsq);

    // phase 7: BN + ELU + skip, fused layer-1 logits
    bn_elu_attn<<<(MPAD * 32 + 255) / 256, 256, 0, stream>>>(
        out0b, h_bf, bnsum, bnsq, gamma0, beta0, b_skip, v, a_s, a_d);

    // phase 8: GEMM1
    dim3 gg1(MPAD / 128, 2);
    gemm_bf16<<<gg1, 256, 0, stream>>>(h_bf, W1t, xp_bf, 256);

    // phase 9: gather1
    gather1<<<(NN * 64 + 255) / 256, 256, 0, stream>>>(adj, rowptr, xp_bf, a_s, a_d, b1, out);
}